// Round 1
// baseline (611.218 us; speedup 1.0000x reference)
//
#include <hip/hip_runtime.h>

#define N_NODES  100000
#define N_EDGES  20000
#define NNZ_     600000
#define N_GRAPHS 64
#define C_       128

// ---------------- CSR build ----------------

__global__ void count_kernel(const int* __restrict__ node_idx, const int* __restrict__ edge_idx,
                             int* __restrict__ ecnt, int* __restrict__ ncnt) {
    int i = blockIdx.x * blockDim.x + threadIdx.x;
    if (i >= NNZ_) return;
    atomicAdd(&ecnt[edge_idx[i]], 1);
    atomicAdd(&ncnt[node_idx[i]], 1);
}

__device__ __forceinline__ int block_incl_scan_256(int v, int* lds) {
    int t = threadIdx.x;
    lds[t] = v; __syncthreads();
    #pragma unroll
    for (int o = 1; o < 256; o <<= 1) {
        int u = (t >= o) ? lds[t - o] : 0;
        __syncthreads();
        v += u;
        lds[t] = v;
        __syncthreads();
    }
    return v;
}

__global__ __launch_bounds__(256) void scan_part(const int* __restrict__ in, int n, int* __restrict__ bsums) {
    __shared__ int lds[256];
    int b = blockIdx.x;
    int base = b * 1024 + threadIdx.x * 4;
    int s = 0;
    #pragma unroll
    for (int j = 0; j < 4; j++) s += (base + j < n) ? in[base + j] : 0;
    int incl = block_incl_scan_256(s, lds);
    if (threadIdx.x == 255) bsums[b] = incl;
}

__global__ __launch_bounds__(256) void scan_sums(int* __restrict__ bsums, int nb) {
    __shared__ int lds[256];
    int t = threadIdx.x;
    int v = (t < nb) ? bsums[t] : 0;
    int incl = block_incl_scan_256(v, lds);
    if (t < nb) bsums[t] = incl - v;   // exclusive
}

__global__ __launch_bounds__(256) void scan_write(const int* __restrict__ in, int n,
                                                  const int* __restrict__ bsums, int* __restrict__ out) {
    __shared__ int lds[256];
    int b = blockIdx.x;
    int base = b * 1024 + threadIdx.x * 4;
    int x[4];
    int ts = 0;
    #pragma unroll
    for (int j = 0; j < 4; j++) { x[j] = (base + j < n) ? in[base + j] : 0; ts += x[j]; }
    int incl = block_incl_scan_256(ts, lds);
    int run = bsums[b] + (incl - ts);
    #pragma unroll
    for (int j = 0; j < 4; j++) {
        if (base + j < n) out[base + j] = run;
        run += x[j];
    }
}

__global__ void fill_csr(const int* __restrict__ node_idx, const int* __restrict__ edge_idx,
                         const int* __restrict__ eoffs, const int* __restrict__ noffs,
                         int* __restrict__ ecur, int* __restrict__ ncur,
                         int* __restrict__ csr_en, int* __restrict__ csr_ne) {
    int i = blockIdx.x * blockDim.x + threadIdx.x;
    if (i >= NNZ_) return;
    int n = node_idx[i], e = edge_idx[i];
    int p = atomicAdd(&ecur[e], 1);
    csr_en[eoffs[e] + p] = n;
    int q = atomicAdd(&ncur[n], 1);
    csr_ne[noffs[n] + q] = e;
}

__global__ void invert_kernel(const int* __restrict__ cnt, float* __restrict__ inv, int n) {
    int i = blockIdx.x * blockDim.x + threadIdx.x;
    if (i >= n) return;
    int c = cnt[i];
    inv[i] = (c > 0) ? 1.0f / (float)c : 0.0f;
}

// ---------------- GEMM: C[M x 128] = A[M x 128] @ W[128 x 128], fp32 ----------------
// block = 256 threads, tile = 32 rows x 128 cols, 4x4 per thread.

__global__ __launch_bounds__(256) void gemm128(const float* __restrict__ A, const float* __restrict__ W,
                                               float* __restrict__ C) {
    __shared__ float Wl[128 * 128];   // [k][col], 64 KB
    __shared__ float Al[32 * 128];    // [row][k] row-major, 16 KB
    int t = threadIdx.x;
    int r0 = blockIdx.x * 32;

    // stage W (16384 floats = 4096 float4)
    #pragma unroll
    for (int i = 0; i < 16; i++)
        ((float4*)Wl)[i * 256 + t] = ((const float4*)W)[i * 256 + t];
    // stage A tile (contiguous 32 rows = 1024 float4)
    const float4* Ag = (const float4*)(A + (size_t)r0 * C_);
    #pragma unroll
    for (int i = 0; i < 4; i++)
        ((float4*)Al)[i * 256 + t] = Ag[i * 256 + t];
    __syncthreads();

    int tc = (t & 31) * 4;        // col base 0..124
    int tr = (t >> 5) * 4;        // row base 0..28
    float acc[4][4] = {};
    const float4* Al4 = (const float4*)Al;

    #pragma unroll 2
    for (int k4 = 0; k4 < 32; k4++) {
        float av[4][4], wv[4][4];
        #pragma unroll
        for (int j = 0; j < 4; j++)
            *(float4*)av[j] = Al4[(tr + j) * 32 + k4];     // row tr+j, k = 4*k4..4*k4+3 (broadcast)
        #pragma unroll
        for (int kk = 0; kk < 4; kk++)
            *(float4*)wv[kk] = *(const float4*)&Wl[(k4 * 4 + kk) * 128 + tc];
        #pragma unroll
        for (int j = 0; j < 4; j++)
            #pragma unroll
            for (int i = 0; i < 4; i++)
                acc[j][i] += av[j][0] * wv[0][i] + av[j][1] * wv[1][i]
                           + av[j][2] * wv[2][i] + av[j][3] * wv[3][i];
    }

    #pragma unroll
    for (int j = 0; j < 4; j++) {
        float4 o = make_float4(acc[j][0], acc[j][1], acc[j][2], acc[j][3]);
        *(float4*)&C[(size_t)(r0 + tr + j) * C_ + tc] = o;
    }
}

// ---------------- segment gathers (1 wave per segment, float2 per lane) ----------------

__global__ __launch_bounds__(256) void gather_edges(const float* __restrict__ X, const int* __restrict__ csr,
                                                    const int* __restrict__ off, const int* __restrict__ cnt,
                                                    const float* __restrict__ binv, float* __restrict__ E) {
    int w = (blockIdx.x * blockDim.x + threadIdx.x) >> 6;
    int lane = threadIdx.x & 63;
    if (w >= N_EDGES) return;
    int s = off[w], n = cnt[w];
    float ax = 0.f, ay = 0.f;
    for (int i = 0; i < n; i++) {
        int node = csr[s + i];
        float2 v = *(const float2*)(X + (size_t)node * C_ + lane * 2);
        ax += v.x; ay += v.y;
    }
    float sc = binv[w];
    float2 r; r.x = ax * sc; r.y = ay * sc;
    *(float2*)(E + (size_t)w * C_ + lane * 2) = r;
}

__global__ __launch_bounds__(256) void gather_nodes(const float* __restrict__ E, const int* __restrict__ csr,
                                                    const int* __restrict__ off, const int* __restrict__ cnt,
                                                    const float* __restrict__ dinv, const float* __restrict__ bias,
                                                    float* __restrict__ Y) {
    int w = (blockIdx.x * blockDim.x + threadIdx.x) >> 6;
    int lane = threadIdx.x & 63;
    if (w >= N_NODES) return;
    int s = off[w], n = cnt[w];
    float ax = 0.f, ay = 0.f;
    for (int i = 0; i < n; i++) {
        int e = csr[s + i];
        float2 v = *(const float2*)(E + (size_t)e * C_ + lane * 2);
        ax += v.x; ay += v.y;
    }
    float sc = dinv[w];
    float2 bb = *(const float2*)(bias + lane * 2);
    float rx = fmaxf(ax * sc + bb.x, 0.f);
    float ry = fmaxf(ay * sc + bb.y, 0.f);
    float2 r; r.x = rx; r.y = ry;
    *(float2*)(Y + (size_t)w * C_ + lane * 2) = r;
}

// ---------------- pooling + head ----------------

__device__ __forceinline__ int lower_bound_dev(const int* __restrict__ a, int n, int key) {
    int lo = 0, hi = n;
    while (lo < hi) { int mid = (lo + hi) >> 1; if (a[mid] < key) lo = mid + 1; else hi = mid; }
    return lo;
}

__global__ __launch_bounds__(128) void pool_kernel(const float* __restrict__ H, const int* __restrict__ batch,
                                                   float* __restrict__ P) {
    int g = blockIdx.x;
    int chunk = blockIdx.y;
    const int NCH = 8;
    __shared__ int s_lo, s_hi;
    if (threadIdx.x == 0) {
        s_lo = lower_bound_dev(batch, N_NODES, g);
        s_hi = lower_bound_dev(batch, N_NODES, g + 1);
    }
    __syncthreads();
    int lo = s_lo, hi = s_hi, len = hi - lo;
    if (len <= 0) return;
    int per = (len + NCH - 1) / NCH;
    int s = lo + chunk * per;
    int e = min(s + per, hi);
    if (s >= e) return;
    float acc = 0.f;
    for (int r = s; r < e; r++) acc += H[(size_t)r * C_ + threadIdx.x];
    atomicAdd(&P[g * C_ + threadIdx.x], acc);
}

__global__ __launch_bounds__(1024) void final_kernel(const float* __restrict__ P, const int* __restrict__ batch,
                                                     const float* __restrict__ Wfc, const float* __restrict__ bfc,
                                                     float* __restrict__ out) {
    int t = threadIdx.x;          // 0..1023
    int r = t >> 4, c = t & 15;
    int lo = lower_bound_dev(batch, N_NODES, r);
    int hi = lower_bound_dev(batch, N_NODES, r + 1);
    float cnt = (float)((hi - lo) > 0 ? (hi - lo) : 1);
    float acc = 0.f;
    #pragma unroll 8
    for (int k = 0; k < C_; k++) acc += P[r * C_ + k] * Wfc[k * 16 + c];
    float logit = acc / cnt + bfc[c];
    __shared__ float l[N_GRAPHS][16];
    l[r][c] = logit;
    __syncthreads();
    float m = -1e30f;
    #pragma unroll
    for (int k = 0; k < 16; k++) m = fmaxf(m, l[r][k]);
    float sum = 0.f;
    #pragma unroll
    for (int k = 0; k < 16; k++) sum += expf(l[r][k] - m);
    out[t] = logit - m - logf(sum);
}

// ---------------- launch ----------------

extern "C" void kernel_launch(void* const* d_in, const int* in_sizes, int n_in,
                              void* d_out, int out_size, void* d_ws, size_t ws_size,
                              hipStream_t stream) {
    const float* x        = (const float*)d_in[0];
    const int*   node_idx = (const int*)  d_in[1];
    const int*   edge_idx = (const int*)  d_in[2];
    const int*   batch    = (const int*)  d_in[3];
    const float* W1       = (const float*)d_in[4];
    const float* b1       = (const float*)d_in[5];
    const float* W2       = (const float*)d_in[6];
    const float* b2       = (const float*)d_in[7];
    const float* Wfc      = (const float*)d_in[8];
    const float* bfc      = (const float*)d_in[9];
    float* out = (float*)d_out;

    char* ws = (char*)d_ws;
    size_t off = 0;
    auto alloc = [&](size_t bytes) -> char* {
        off = (off + 255) & ~(size_t)255;
        char* p = ws + off;
        off += bytes;
        return p;
    };

    float* xw     = (float*)alloc((size_t)N_NODES * C_ * 4);
    float* hb     = (float*)alloc((size_t)N_NODES * C_ * 4);
    float* eb     = (float*)alloc((size_t)N_EDGES * C_ * 4);
    // zero-region start
    int*   ecnt   = (int*)  alloc((size_t)N_EDGES * 4);
    int*   ncnt   = (int*)  alloc((size_t)N_NODES * 4);
    int*   ecur   = (int*)  alloc((size_t)N_EDGES * 4);
    int*   ncur   = (int*)  alloc((size_t)N_NODES * 4);
    float* pooled = (float*)alloc((size_t)N_GRAPHS * C_ * 4);
    char*  zend   = ws + off;
    // zero-region end
    int*   eoffs  = (int*)  alloc((size_t)N_EDGES * 4);
    int*   noffs  = (int*)  alloc((size_t)N_NODES * 4);
    int*   csr_en = (int*)  alloc((size_t)NNZ_ * 4);
    int*   csr_ne = (int*)  alloc((size_t)NNZ_ * 4);
    float* binv   = (float*)alloc((size_t)N_EDGES * 4);
    float* dinv   = (float*)alloc((size_t)N_NODES * 4);
    int*   bsum   = (int*)  alloc((size_t)1024 * 4);

    hipMemsetAsync((void*)ecnt, 0, (size_t)(zend - (char*)ecnt), stream);

    // CSR build
    count_kernel<<<(NNZ_ + 255) / 256, 256, 0, stream>>>(node_idx, edge_idx, ecnt, ncnt);
    const int NB_E = (N_EDGES + 1023) / 1024;   // 20
    const int NB_N = (N_NODES + 1023) / 1024;   // 98
    scan_part <<<NB_E, 256, 0, stream>>>(ecnt, N_EDGES, bsum);
    scan_sums <<<1,    256, 0, stream>>>(bsum, NB_E);
    scan_write<<<NB_E, 256, 0, stream>>>(ecnt, N_EDGES, bsum, eoffs);
    scan_part <<<NB_N, 256, 0, stream>>>(ncnt, N_NODES, bsum);
    scan_sums <<<1,    256, 0, stream>>>(bsum, NB_N);
    scan_write<<<NB_N, 256, 0, stream>>>(ncnt, N_NODES, bsum, noffs);
    fill_csr<<<(NNZ_ + 255) / 256, 256, 0, stream>>>(node_idx, edge_idx, eoffs, noffs,
                                                     ecur, ncur, csr_en, csr_ne);
    invert_kernel<<<(N_EDGES + 255) / 256, 256, 0, stream>>>(ecnt, binv, N_EDGES);
    invert_kernel<<<(N_NODES + 255) / 256, 256, 0, stream>>>(ncnt, dinv, N_NODES);

    // layer 1
    gemm128<<<N_NODES / 32, 256, 0, stream>>>(x, W1, xw);
    gather_edges<<<N_EDGES / 4, 256, 0, stream>>>(xw, csr_en, eoffs, ecnt, binv, eb);
    gather_nodes<<<N_NODES / 4, 256, 0, stream>>>(eb, csr_ne, noffs, ncnt, dinv, b1, hb);
    // layer 2
    gemm128<<<N_NODES / 32, 256, 0, stream>>>(hb, W2, xw);
    gather_edges<<<N_EDGES / 4, 256, 0, stream>>>(xw, csr_en, eoffs, ecnt, binv, eb);
    gather_nodes<<<N_NODES / 4, 256, 0, stream>>>(eb, csr_ne, noffs, ncnt, dinv, b2, hb);
    // head
    pool_kernel<<<dim3(N_GRAPHS, 8), 128, 0, stream>>>(hb, batch, pooled);
    final_kernel<<<1, 1024, 0, stream>>>(pooled, batch, Wfc, bfc, out);
}

// Round 2
// 399.485 us; speedup vs baseline: 1.5300x; 1.5300x over previous
//
#include <hip/hip_runtime.h>

#define N_NODES  100000
#define N_EDGES  20000
#define NNZ_     600000
#define N_GRAPHS 64
#define C_       128

typedef unsigned short ushort_t;
typedef unsigned int   uint_t;
typedef __attribute__((ext_vector_type(8))) short bf16x8;
typedef __attribute__((ext_vector_type(8))) unsigned short u16x8;
typedef __attribute__((ext_vector_type(4))) float f32x4;

// bf16 helpers (manual RNE; inputs are finite)
__device__ __forceinline__ ushort_t f2bf(float f) {
    uint_t u = __float_as_uint(f);
    u += 0x7fffu + ((u >> 16) & 1u);
    return (ushort_t)(u >> 16);
}
__device__ __forceinline__ float bf2f(ushort_t u) {
    return __uint_as_float(((uint_t)u) << 16);
}
__device__ __forceinline__ float bflo(uint_t v) { return __uint_as_float(v << 16); }
__device__ __forceinline__ float bfhi(uint_t v) { return __uint_as_float(v & 0xffff0000u); }

// ---------------- CSR build ----------------

__global__ void count_kernel(const int* __restrict__ node_idx, const int* __restrict__ edge_idx,
                             int* __restrict__ ecnt, int* __restrict__ ncnt) {
    int i = blockIdx.x * blockDim.x + threadIdx.x;
    if (i >= NNZ_) return;
    atomicAdd(&ecnt[edge_idx[i]], 1);
    atomicAdd(&ncnt[node_idx[i]], 1);
}

__device__ __forceinline__ int block_incl_scan_256(int v, int* lds) {
    int t = threadIdx.x;
    lds[t] = v; __syncthreads();
    #pragma unroll
    for (int o = 1; o < 256; o <<= 1) {
        int u = (t >= o) ? lds[t - o] : 0;
        __syncthreads();
        v += u;
        lds[t] = v;
        __syncthreads();
    }
    return v;
}

__global__ __launch_bounds__(256) void scan_part(const int* __restrict__ in, int n, int* __restrict__ bsums) {
    __shared__ int lds[256];
    int b = blockIdx.x;
    int base = b * 1024 + threadIdx.x * 4;
    int s = 0;
    #pragma unroll
    for (int j = 0; j < 4; j++) s += (base + j < n) ? in[base + j] : 0;
    int incl = block_incl_scan_256(s, lds);
    if (threadIdx.x == 255) bsums[b] = incl;
}

__global__ __launch_bounds__(256) void scan_sums(int* __restrict__ bsums, int nb) {
    __shared__ int lds[256];
    int t = threadIdx.x;
    int v = (t < nb) ? bsums[t] : 0;
    int incl = block_incl_scan_256(v, lds);
    if (t < nb) bsums[t] = incl - v;   // exclusive
}

__global__ __launch_bounds__(256) void scan_write(const int* __restrict__ in, int n,
                                                  const int* __restrict__ bsums, int* __restrict__ out) {
    __shared__ int lds[256];
    int b = blockIdx.x;
    int base = b * 1024 + threadIdx.x * 4;
    int x[4];
    int ts = 0;
    #pragma unroll
    for (int j = 0; j < 4; j++) { x[j] = (base + j < n) ? in[base + j] : 0; ts += x[j]; }
    int incl = block_incl_scan_256(ts, lds);
    int run = bsums[b] + (incl - ts);
    #pragma unroll
    for (int j = 0; j < 4; j++) {
        if (base + j < n) out[base + j] = run;
        run += x[j];
    }
}

__global__ void fill_csr(const int* __restrict__ node_idx, const int* __restrict__ edge_idx,
                         const int* __restrict__ eoffs, const int* __restrict__ noffs,
                         int* __restrict__ ecur, int* __restrict__ ncur,
                         int* __restrict__ csr_en, int* __restrict__ csr_ne) {
    int i = blockIdx.x * blockDim.x + threadIdx.x;
    if (i >= NNZ_) return;
    int n = node_idx[i], e = edge_idx[i];
    int p = atomicAdd(&ecur[e], 1);
    csr_en[eoffs[e] + p] = n;
    int q = atomicAdd(&ncur[n], 1);
    csr_ne[noffs[n] + q] = e;
}

__global__ void invert_kernel(const int* __restrict__ cnt, float* __restrict__ inv, int n) {
    int i = blockIdx.x * blockDim.x + threadIdx.x;
    if (i >= n) return;
    int c = cnt[i];
    inv[i] = (c > 0) ? 1.0f / (float)c : 0.0f;
}

// ---------------- weight transpose+convert: WT[n][k] = bf16(W[k][n]) ----------------

__global__ __launch_bounds__(256) void conv_wt(const float* __restrict__ W, ushort_t* __restrict__ WT) {
    int idx = blockIdx.x * 256 + threadIdx.x;   // 0..16383
    int n = idx >> 7, k = idx & 127;
    WT[n * 128 + k] = f2bf(W[k * 128 + n]);
}

// ---------------- MFMA GEMM: C[M x 128] = A[M x 128] @ W[128 x 128] (bf16 in/out) ----------
// block = 256 threads (4 waves); tile 64 rows x 128 cols; wave computes 16 rows x 128 cols.
// 16x16x32 bf16 MFMA. XOR-swizzled LDS (16B slot index ^ (row&7)) -> conflict-free b128 reads.

template<bool AF32>
__global__ __launch_bounds__(256) void gemm_mfma(const void* __restrict__ Ap,
                                                 const ushort_t* __restrict__ WT,
                                                 ushort_t* __restrict__ Cb, int M) {
    __shared__ ushort_t Wl[128 * 128];   // 32 KB, W^T: [n][k]
    __shared__ ushort_t Al[64 * 128];    // 16 KB, [row][k]
    int t = threadIdx.x;
    int r0 = blockIdx.x * 64;

    // stage W^T (2048 x 16B chunks, 8 per thread), swizzled
    const uint4* WTg = (const uint4*)WT;
    #pragma unroll
    for (int i = 0; i < 8; i++) {
        int c = i * 256 + t;
        int row = c >> 4, colel = (c & 15) * 8;
        *(uint4*)&Wl[row * 128 + (colel ^ ((row & 7) << 3))] = WTg[c];
    }
    // stage A tile (1024 x 16B chunks, 4 per thread), swizzled, convert if f32
    #pragma unroll
    for (int i = 0; i < 4; i++) {
        int c = i * 256 + t;
        int row = c >> 4;
        int colel = (c & 15) * 8;
        int gr = r0 + row; if (gr >= M) gr = M - 1;
        u16x8 v;
        if (AF32) {
            const float* Af = (const float*)Ap + (size_t)gr * 128 + colel;
            float4 f0 = *(const float4*)Af;
            float4 f1 = *(const float4*)(Af + 4);
            v[0] = f2bf(f0.x); v[1] = f2bf(f0.y); v[2] = f2bf(f0.z); v[3] = f2bf(f0.w);
            v[4] = f2bf(f1.x); v[5] = f2bf(f1.y); v[6] = f2bf(f1.z); v[7] = f2bf(f1.w);
        } else {
            v = *(const u16x8*)((const ushort_t*)Ap + (size_t)gr * 128 + colel);
        }
        *(u16x8*)&Al[row * 128 + (colel ^ ((row & 7) << 3))] = v;
    }
    __syncthreads();

    int lane = t & 63, wid = t >> 6;
    int arow = wid * 16 + (lane & 15);
    int kq = lane >> 4;                // 0..3
    f32x4 acc[8] = {};

    #pragma unroll
    for (int ks = 0; ks < 4; ks++) {
        int colel = ks * 32 + kq * 8;
        bf16x8 a = *(const bf16x8*)&Al[arow * 128 + (colel ^ ((arow & 7) << 3))];
        #pragma unroll
        for (int nt = 0; nt < 8; nt++) {
            int wr = nt * 16 + (lane & 15);
            bf16x8 b = *(const bf16x8*)&Wl[wr * 128 + (colel ^ ((wr & 7) << 3))];
            acc[nt] = __builtin_amdgcn_mfma_f32_16x16x32_bf16(a, b, acc[nt], 0, 0, 0);
        }
    }

    // C/D layout: col = lane&15, row = kq*4 + j
    #pragma unroll
    for (int nt = 0; nt < 8; nt++) {
        #pragma unroll
        for (int j = 0; j < 4; j++) {
            int gr = r0 + wid * 16 + kq * 4 + j;
            if (gr < M) Cb[(size_t)gr * 128 + nt * 16 + (lane & 15)] = f2bf(acc[nt][j]);
        }
    }
}

// ---------------- segment gathers (1 wave per segment, bf16x2 per lane, unroll-4) ----------

__global__ __launch_bounds__(256) void gather_edges_bf(const ushort_t* __restrict__ X,
                                                       const int* __restrict__ csr,
                                                       const int* __restrict__ off, const int* __restrict__ cnt,
                                                       const float* __restrict__ binv,
                                                       ushort_t* __restrict__ E) {
    int w = (blockIdx.x * blockDim.x + threadIdx.x) >> 6;
    int lane = threadIdx.x & 63;
    if (w >= N_EDGES) return;
    int s = off[w], n = cnt[w];
    const uint_t* Xu = (const uint_t*)X;   // row stride 64 u32
    float ax = 0.f, ay = 0.f;
    int i = 0;
    for (; i + 4 <= n; i += 4) {
        int n0 = csr[s + i], n1 = csr[s + i + 1], n2 = csr[s + i + 2], n3 = csr[s + i + 3];
        uint_t v0 = Xu[(size_t)n0 * 64 + lane];
        uint_t v1 = Xu[(size_t)n1 * 64 + lane];
        uint_t v2 = Xu[(size_t)n2 * 64 + lane];
        uint_t v3 = Xu[(size_t)n3 * 64 + lane];
        ax += bflo(v0) + bflo(v1) + bflo(v2) + bflo(v3);
        ay += bfhi(v0) + bfhi(v1) + bfhi(v2) + bfhi(v3);
    }
    for (; i < n; i++) {
        uint_t v = Xu[(size_t)csr[s + i] * 64 + lane];
        ax += bflo(v); ay += bfhi(v);
    }
    float sc = binv[w];
    uint_t r = ((uint_t)f2bf(ay * sc) << 16) | f2bf(ax * sc);
    ((uint_t*)E)[(size_t)w * 64 + lane] = r;
}

__global__ __launch_bounds__(256) void gather_nodes_bf(const ushort_t* __restrict__ E,
                                                       const int* __restrict__ csr,
                                                       const int* __restrict__ off, const int* __restrict__ cnt,
                                                       const float* __restrict__ dinv,
                                                       const float* __restrict__ bias,
                                                       ushort_t* __restrict__ Y) {
    int w = (blockIdx.x * blockDim.x + threadIdx.x) >> 6;
    int lane = threadIdx.x & 63;
    if (w >= N_NODES) return;
    int s = off[w], n = cnt[w];
    const uint_t* Eu = (const uint_t*)E;
    float ax = 0.f, ay = 0.f;
    int i = 0;
    for (; i + 4 <= n; i += 4) {
        int e0 = csr[s + i], e1 = csr[s + i + 1], e2 = csr[s + i + 2], e3 = csr[s + i + 3];
        uint_t v0 = Eu[(size_t)e0 * 64 + lane];
        uint_t v1 = Eu[(size_t)e1 * 64 + lane];
        uint_t v2 = Eu[(size_t)e2 * 64 + lane];
        uint_t v3 = Eu[(size_t)e3 * 64 + lane];
        ax += bflo(v0) + bflo(v1) + bflo(v2) + bflo(v3);
        ay += bfhi(v0) + bfhi(v1) + bfhi(v2) + bfhi(v3);
    }
    for (; i < n; i++) {
        uint_t v = Eu[(size_t)csr[s + i] * 64 + lane];
        ax += bflo(v); ay += bfhi(v);
    }
    float sc = dinv[w];
    float rx = fmaxf(ax * sc + bias[lane * 2],     0.f);
    float ry = fmaxf(ay * sc + bias[lane * 2 + 1], 0.f);
    uint_t r = ((uint_t)f2bf(ry) << 16) | f2bf(rx);
    ((uint_t*)Y)[(size_t)w * 64 + lane] = r;
}

// ---------------- pooling + head ----------------

__device__ __forceinline__ int lower_bound_dev(const int* __restrict__ a, int n, int key) {
    int lo = 0, hi = n;
    while (lo < hi) { int mid = (lo + hi) >> 1; if (a[mid] < key) lo = mid + 1; else hi = mid; }
    return lo;
}

__global__ __launch_bounds__(128) void pool_kernel(const ushort_t* __restrict__ H, const int* __restrict__ batch,
                                                   float* __restrict__ P) {
    int g = blockIdx.x;
    int chunk = blockIdx.y;
    const int NCH = 8;
    __shared__ int s_lo, s_hi;
    if (threadIdx.x == 0) {
        s_lo = lower_bound_dev(batch, N_NODES, g);
        s_hi = lower_bound_dev(batch, N_NODES, g + 1);
    }
    __syncthreads();
    int lo = s_lo, hi = s_hi, len = hi - lo;
    if (len <= 0) return;
    int per = (len + NCH - 1) / NCH;
    int s = lo + chunk * per;
    int e = min(s + per, hi);
    if (s >= e) return;
    float acc = 0.f;
    for (int r = s; r < e; r++) acc += bf2f(H[(size_t)r * C_ + threadIdx.x]);
    atomicAdd(&P[g * C_ + threadIdx.x], acc);
}

__global__ __launch_bounds__(1024) void final_kernel(const float* __restrict__ P, const int* __restrict__ batch,
                                                     const float* __restrict__ Wfc, const float* __restrict__ bfc,
                                                     float* __restrict__ out) {
    int t = threadIdx.x;          // 0..1023
    int r = t >> 4, c = t & 15;
    int lo = lower_bound_dev(batch, N_NODES, r);
    int hi = lower_bound_dev(batch, N_NODES, r + 1);
    float cnt = (float)((hi - lo) > 0 ? (hi - lo) : 1);
    float acc = 0.f;
    #pragma unroll 8
    for (int k = 0; k < C_; k++) acc += P[r * C_ + k] * Wfc[k * 16 + c];
    float logit = acc / cnt + bfc[c];
    __shared__ float l[N_GRAPHS][16];
    l[r][c] = logit;
    __syncthreads();
    float m = -1e30f;
    #pragma unroll
    for (int k = 0; k < 16; k++) m = fmaxf(m, l[r][k]);
    float sum = 0.f;
    #pragma unroll
    for (int k = 0; k < 16; k++) sum += expf(l[r][k] - m);
    out[t] = logit - m - logf(sum);
}

// ---------------- launch ----------------

extern "C" void kernel_launch(void* const* d_in, const int* in_sizes, int n_in,
                              void* d_out, int out_size, void* d_ws, size_t ws_size,
                              hipStream_t stream) {
    const float* x        = (const float*)d_in[0];
    const int*   node_idx = (const int*)  d_in[1];
    const int*   edge_idx = (const int*)  d_in[2];
    const int*   batch    = (const int*)  d_in[3];
    const float* W1       = (const float*)d_in[4];
    const float* b1       = (const float*)d_in[5];
    const float* W2       = (const float*)d_in[6];
    const float* b2       = (const float*)d_in[7];
    const float* Wfc      = (const float*)d_in[8];
    const float* bfc      = (const float*)d_in[9];
    float* out = (float*)d_out;

    char* ws = (char*)d_ws;
    size_t off = 0;
    auto alloc = [&](size_t bytes) -> char* {
        off = (off + 255) & ~(size_t)255;
        char* p = ws + off;
        off += bytes;
        return p;
    };

    ushort_t* xwb  = (ushort_t*)alloc((size_t)N_NODES * C_ * 2);   // GEMM outputs (bf16)
    ushort_t* hbb  = (ushort_t*)alloc((size_t)N_NODES * C_ * 2);   // conv outputs (bf16)
    ushort_t* ebb  = (ushort_t*)alloc((size_t)N_EDGES * C_ * 2);   // edge features (bf16)
    ushort_t* wt1  = (ushort_t*)alloc((size_t)C_ * C_ * 2);
    ushort_t* wt2  = (ushort_t*)alloc((size_t)C_ * C_ * 2);
    // zero-region start
    int*   ecnt   = (int*)  alloc((size_t)N_EDGES * 4);
    int*   ncnt   = (int*)  alloc((size_t)N_NODES * 4);
    int*   ecur   = (int*)  alloc((size_t)N_EDGES * 4);
    int*   ncur   = (int*)  alloc((size_t)N_NODES * 4);
    float* pooled = (float*)alloc((size_t)N_GRAPHS * C_ * 4);
    char*  zend   = ws + off;
    // zero-region end
    int*   eoffs  = (int*)  alloc((size_t)N_EDGES * 4);
    int*   noffs  = (int*)  alloc((size_t)N_NODES * 4);
    int*   csr_en = (int*)  alloc((size_t)NNZ_ * 4);
    int*   csr_ne = (int*)  alloc((size_t)NNZ_ * 4);
    float* binv   = (float*)alloc((size_t)N_EDGES * 4);
    float* dinv   = (float*)alloc((size_t)N_NODES * 4);
    int*   bsum   = (int*)  alloc((size_t)1024 * 4);

    hipMemsetAsync((void*)ecnt, 0, (size_t)(zend - (char*)ecnt), stream);

    // CSR build
    count_kernel<<<(NNZ_ + 255) / 256, 256, 0, stream>>>(node_idx, edge_idx, ecnt, ncnt);
    const int NB_E = (N_EDGES + 1023) / 1024;   // 20
    const int NB_N = (N_NODES + 1023) / 1024;   // 98
    scan_part <<<NB_E, 256, 0, stream>>>(ecnt, N_EDGES, bsum);
    scan_sums <<<1,    256, 0, stream>>>(bsum, NB_E);
    scan_write<<<NB_E, 256, 0, stream>>>(ecnt, N_EDGES, bsum, eoffs);
    scan_part <<<NB_N, 256, 0, stream>>>(ncnt, N_NODES, bsum);
    scan_sums <<<1,    256, 0, stream>>>(bsum, NB_N);
    scan_write<<<NB_N, 256, 0, stream>>>(ncnt, N_NODES, bsum, noffs);
    fill_csr<<<(NNZ_ + 255) / 256, 256, 0, stream>>>(node_idx, edge_idx, eoffs, noffs,
                                                     ecur, ncur, csr_en, csr_ne);
    invert_kernel<<<(N_EDGES + 255) / 256, 256, 0, stream>>>(ecnt, binv, N_EDGES);
    invert_kernel<<<(N_NODES + 255) / 256, 256, 0, stream>>>(ncnt, dinv, N_NODES);

    // weights -> bf16 transposed
    conv_wt<<<64, 256, 0, stream>>>(W1, wt1);
    conv_wt<<<64, 256, 0, stream>>>(W2, wt2);

    const int GB = (N_NODES + 63) / 64;   // gemm blocks
    // layer 1
    gemm_mfma<true ><<<GB, 256, 0, stream>>>(x, wt1, xwb, N_NODES);
    gather_edges_bf<<<N_EDGES / 4, 256, 0, stream>>>(xwb, csr_en, eoffs, ecnt, binv, ebb);
    gather_nodes_bf<<<N_NODES / 4, 256, 0, stream>>>(ebb, csr_ne, noffs, ncnt, dinv, b1, hbb);
    // layer 2
    gemm_mfma<false><<<GB, 256, 0, stream>>>(hbb, wt2, xwb, N_NODES);
    gather_edges_bf<<<N_EDGES / 4, 256, 0, stream>>>(xwb, csr_en, eoffs, ecnt, binv, ebb);
    gather_nodes_bf<<<N_NODES / 4, 256, 0, stream>>>(ebb, csr_ne, noffs, ncnt, dinv, b2, hbb);
    // head
    pool_kernel<<<dim3(N_GRAPHS, 8), 128, 0, stream>>>(hbb, batch, pooled);
    final_kernel<<<1, 1024, 0, stream>>>(pooled, batch, Wfc, bfc, out);
}

// Round 3
// 388.253 us; speedup vs baseline: 1.5743x; 1.0289x over previous
//
#include <hip/hip_runtime.h>

#define N_NODES  100000
#define N_EDGES  20000
#define NNZ_     600000
#define N_GRAPHS 64
#define C_       128

typedef unsigned short ushort_t;
typedef unsigned int   uint_t;
typedef __attribute__((ext_vector_type(8))) short bf16x8;
typedef __attribute__((ext_vector_type(8))) unsigned short u16x8;
typedef __attribute__((ext_vector_type(4))) float f32x4;

// bf16 helpers (manual RNE; inputs are finite)
__device__ __forceinline__ ushort_t f2bf(float f) {
    uint_t u = __float_as_uint(f);
    u += 0x7fffu + ((u >> 16) & 1u);
    return (ushort_t)(u >> 16);
}
__device__ __forceinline__ float bf2f(ushort_t u) {
    return __uint_as_float(((uint_t)u) << 16);
}
__device__ __forceinline__ float bflo(uint_t v) { return __uint_as_float(v << 16); }
__device__ __forceinline__ float bfhi(uint_t v) { return __uint_as_float(v & 0xffff0000u); }

// ---------------- CSR build ----------------

__global__ void count_kernel(const int* __restrict__ node_idx, const int* __restrict__ edge_idx,
                             int* __restrict__ ecnt, int* __restrict__ ncnt) {
    int i = blockIdx.x * blockDim.x + threadIdx.x;
    if (i >= NNZ_) return;
    atomicAdd(&ecnt[edge_idx[i]], 1);
    atomicAdd(&ncnt[node_idx[i]], 1);
}

__device__ __forceinline__ int block_incl_scan_256(int v, int* lds) {
    int t = threadIdx.x;
    lds[t] = v; __syncthreads();
    #pragma unroll
    for (int o = 1; o < 256; o <<= 1) {
        int u = (t >= o) ? lds[t - o] : 0;
        __syncthreads();
        v += u;
        lds[t] = v;
        __syncthreads();
    }
    return v;
}

__global__ __launch_bounds__(256) void scan_part(const int* __restrict__ in, int n, int* __restrict__ bsums) {
    __shared__ int lds[256];
    int b = blockIdx.x;
    int base = b * 1024 + threadIdx.x * 4;
    int s = 0;
    #pragma unroll
    for (int j = 0; j < 4; j++) s += (base + j < n) ? in[base + j] : 0;
    int incl = block_incl_scan_256(s, lds);
    if (threadIdx.x == 255) bsums[b] = incl;
}

__global__ __launch_bounds__(256) void scan_sums(int* __restrict__ bsums, int nb) {
    __shared__ int lds[256];
    int t = threadIdx.x;
    int v = (t < nb) ? bsums[t] : 0;
    int incl = block_incl_scan_256(v, lds);
    if (t < nb) bsums[t] = incl - v;   // exclusive
}

__global__ __launch_bounds__(256) void scan_write(const int* __restrict__ in, int n,
                                                  const int* __restrict__ bsums, int* __restrict__ out) {
    __shared__ int lds[256];
    int b = blockIdx.x;
    int base = b * 1024 + threadIdx.x * 4;
    int x[4];
    int ts = 0;
    #pragma unroll
    for (int j = 0; j < 4; j++) { x[j] = (base + j < n) ? in[base + j] : 0; ts += x[j]; }
    int incl = block_incl_scan_256(ts, lds);
    int run = bsums[b] + (incl - ts);
    #pragma unroll
    for (int j = 0; j < 4; j++) {
        if (base + j < n) out[base + j] = run;
        run += x[j];
    }
}

__global__ void fill_csr(const int* __restrict__ node_idx, const int* __restrict__ edge_idx,
                         const int* __restrict__ eoffs, const int* __restrict__ noffs,
                         int* __restrict__ ecur, int* __restrict__ ncur,
                         int* __restrict__ csr_en, int* __restrict__ csr_ne) {
    int i = blockIdx.x * blockDim.x + threadIdx.x;
    if (i >= NNZ_) return;
    int n = node_idx[i], e = edge_idx[i];
    int p = atomicAdd(&ecur[e], 1);
    csr_en[eoffs[e] + p] = n;
    int q = atomicAdd(&ncur[n], 1);
    csr_ne[noffs[n] + q] = e;
}

__global__ void invert_kernel(const int* __restrict__ cnt, float* __restrict__ inv, int n) {
    int i = blockIdx.x * blockDim.x + threadIdx.x;
    if (i >= n) return;
    int c = cnt[i];
    inv[i] = (c > 0) ? 1.0f / (float)c : 0.0f;
}

// ---------------- conversions ----------------

// WT[n][k] = bf16(W[k][n])
__global__ __launch_bounds__(256) void conv_wt(const float* __restrict__ W, ushort_t* __restrict__ WT) {
    int idx = blockIdx.x * 256 + threadIdx.x;   // 0..16383
    int n = idx >> 7, k = idx & 127;
    WT[n * 128 + k] = f2bf(W[k * 128 + n]);
}

// x (f32) -> xb (bf16), 8 elements/thread
__global__ __launch_bounds__(256) void conv_xb(const float* __restrict__ X, ushort_t* __restrict__ XB) {
    size_t c = (size_t)blockIdx.x * 256 + threadIdx.x;   // chunk of 8
    size_t base = c * 8;
    if (base >= (size_t)N_NODES * C_) return;
    float4 f0 = *(const float4*)(X + base);
    float4 f1 = *(const float4*)(X + base + 4);
    u16x8 v;
    v[0] = f2bf(f0.x); v[1] = f2bf(f0.y); v[2] = f2bf(f0.z); v[3] = f2bf(f0.w);
    v[4] = f2bf(f1.x); v[5] = f2bf(f1.y); v[6] = f2bf(f1.z); v[7] = f2bf(f1.w);
    *(u16x8*)(XB + base) = v;
}

// ---------------- MFMA GEMM: C[M x 128] = A[M x 128] @ W[128 x 128] (bf16 in/out) ----------
// block = 256 threads (4 waves); tile 64 rows x 128 cols; wave computes 16 rows x 128 cols.

__global__ __launch_bounds__(256) void gemm_mfma(const ushort_t* __restrict__ Ab,
                                                 const ushort_t* __restrict__ WT,
                                                 ushort_t* __restrict__ Cb, int M) {
    __shared__ ushort_t Wl[128 * 128];   // 32 KB, W^T: [n][k]
    __shared__ ushort_t Al[64 * 128];    // 16 KB, [row][k]
    int t = threadIdx.x;
    int r0 = blockIdx.x * 64;

    // stage W^T (2048 x 16B chunks, 8 per thread), swizzled
    const uint4* WTg = (const uint4*)WT;
    #pragma unroll
    for (int i = 0; i < 8; i++) {
        int c = i * 256 + t;
        int row = c >> 4, colel = (c & 15) * 8;
        *(uint4*)&Wl[row * 128 + (colel ^ ((row & 7) << 3))] = WTg[c];
    }
    // stage A tile (1024 x 16B chunks, 4 per thread), swizzled
    #pragma unroll
    for (int i = 0; i < 4; i++) {
        int c = i * 256 + t;
        int row = c >> 4;
        int colel = (c & 15) * 8;
        int gr = r0 + row; if (gr >= M) gr = M - 1;
        u16x8 v = *(const u16x8*)(Ab + (size_t)gr * 128 + colel);
        *(u16x8*)&Al[row * 128 + (colel ^ ((row & 7) << 3))] = v;
    }
    __syncthreads();

    int lane = t & 63, wid = t >> 6;
    int arow = wid * 16 + (lane & 15);
    int kq = lane >> 4;                // 0..3
    f32x4 acc[8] = {};

    #pragma unroll
    for (int ks = 0; ks < 4; ks++) {
        int colel = ks * 32 + kq * 8;
        bf16x8 a = *(const bf16x8*)&Al[arow * 128 + (colel ^ ((arow & 7) << 3))];
        #pragma unroll
        for (int nt = 0; nt < 8; nt++) {
            int wr = nt * 16 + (lane & 15);
            bf16x8 b = *(const bf16x8*)&Wl[wr * 128 + (colel ^ ((wr & 7) << 3))];
            acc[nt] = __builtin_amdgcn_mfma_f32_16x16x32_bf16(a, b, acc[nt], 0, 0, 0);
        }
    }

    // C/D layout: col = lane&15, row = kq*4 + j
    #pragma unroll
    for (int nt = 0; nt < 8; nt++) {
        #pragma unroll
        for (int j = 0; j < 4; j++) {
            int gr = r0 + wid * 16 + kq * 4 + j;
            if (gr < M) Cb[(size_t)gr * 128 + nt * 16 + (lane & 15)] = f2bf(acc[nt][j]);
        }
    }
}

// ---------------- segment gathers (1 wave per segment, bf16x2 per lane, unroll-4) ----------

__global__ __launch_bounds__(256) void gather_edges_bf(const ushort_t* __restrict__ X,
                                                       const int* __restrict__ csr,
                                                       const int* __restrict__ off, const int* __restrict__ cnt,
                                                       const float* __restrict__ binv,
                                                       ushort_t* __restrict__ E) {
    int w = (blockIdx.x * blockDim.x + threadIdx.x) >> 6;
    int lane = threadIdx.x & 63;
    if (w >= N_EDGES) return;
    int s = off[w], n = cnt[w];
    const uint_t* Xu = (const uint_t*)X;   // row stride 64 u32
    float ax = 0.f, ay = 0.f;
    int i = 0;
    for (; i + 4 <= n; i += 4) {
        int n0 = csr[s + i], n1 = csr[s + i + 1], n2 = csr[s + i + 2], n3 = csr[s + i + 3];
        uint_t v0 = Xu[(size_t)n0 * 64 + lane];
        uint_t v1 = Xu[(size_t)n1 * 64 + lane];
        uint_t v2 = Xu[(size_t)n2 * 64 + lane];
        uint_t v3 = Xu[(size_t)n3 * 64 + lane];
        ax += bflo(v0) + bflo(v1) + bflo(v2) + bflo(v3);
        ay += bfhi(v0) + bfhi(v1) + bfhi(v2) + bfhi(v3);
    }
    for (; i < n; i++) {
        uint_t v = Xu[(size_t)csr[s + i] * 64 + lane];
        ax += bflo(v); ay += bfhi(v);
    }
    float sc = binv[w];
    uint_t r = ((uint_t)f2bf(ay * sc) << 16) | f2bf(ax * sc);
    ((uint_t*)E)[(size_t)w * 64 + lane] = r;
}

__global__ __launch_bounds__(256) void gather_nodes_bf(const ushort_t* __restrict__ E,
                                                       const int* __restrict__ csr,
                                                       const int* __restrict__ off, const int* __restrict__ cnt,
                                                       const float* __restrict__ dinv,
                                                       const float* __restrict__ bias,
                                                       ushort_t* __restrict__ Y) {
    int w = (blockIdx.x * blockDim.x + threadIdx.x) >> 6;
    int lane = threadIdx.x & 63;
    if (w >= N_NODES) return;
    int s = off[w], n = cnt[w];
    const uint_t* Eu = (const uint_t*)E;
    float ax = 0.f, ay = 0.f;
    int i = 0;
    for (; i + 4 <= n; i += 4) {
        int e0 = csr[s + i], e1 = csr[s + i + 1], e2 = csr[s + i + 2], e3 = csr[s + i + 3];
        uint_t v0 = Eu[(size_t)e0 * 64 + lane];
        uint_t v1 = Eu[(size_t)e1 * 64 + lane];
        uint_t v2 = Eu[(size_t)e2 * 64 + lane];
        uint_t v3 = Eu[(size_t)e3 * 64 + lane];
        ax += bflo(v0) + bflo(v1) + bflo(v2) + bflo(v3);
        ay += bfhi(v0) + bfhi(v1) + bfhi(v2) + bfhi(v3);
    }
    for (; i < n; i++) {
        uint_t v = Eu[(size_t)csr[s + i] * 64 + lane];
        ax += bflo(v); ay += bfhi(v);
    }
    float sc = dinv[w];
    float rx = fmaxf(ax * sc + bias[lane * 2],     0.f);
    float ry = fmaxf(ay * sc + bias[lane * 2 + 1], 0.f);
    uint_t r = ((uint_t)f2bf(ry) << 16) | f2bf(rx);
    ((uint_t*)Y)[(size_t)w * 64 + lane] = r;
}

// ---------------- pooling + head ----------------

__device__ __forceinline__ int lower_bound_dev(const int* __restrict__ a, int n, int key) {
    int lo = 0, hi = n;
    while (lo < hi) { int mid = (lo + hi) >> 1; if (a[mid] < key) lo = mid + 1; else hi = mid; }
    return lo;
}

__global__ __launch_bounds__(128) void pool_kernel(const ushort_t* __restrict__ H, const int* __restrict__ batch,
                                                   float* __restrict__ P) {
    int g = blockIdx.x;
    int chunk = blockIdx.y;
    const int NCH = 8;
    __shared__ int s_lo, s_hi;
    if (threadIdx.x == 0) {
        s_lo = lower_bound_dev(batch, N_NODES, g);
        s_hi = lower_bound_dev(batch, N_NODES, g + 1);
    }
    __syncthreads();
    int lo = s_lo, hi = s_hi, len = hi - lo;
    if (len <= 0) return;
    int per = (len + NCH - 1) / NCH;
    int s = lo + chunk * per;
    int e = min(s + per, hi);
    if (s >= e) return;
    float acc = 0.f;
    for (int r = s; r < e; r++) acc += bf2f(H[(size_t)r * C_ + threadIdx.x]);
    atomicAdd(&P[g * C_ + threadIdx.x], acc);
}

__global__ __launch_bounds__(1024) void final_kernel(const float* __restrict__ P, const int* __restrict__ batch,
                                                     const float* __restrict__ Wfc, const float* __restrict__ bfc,
                                                     float* __restrict__ out) {
    int t = threadIdx.x;          // 0..1023
    int r = t >> 4, c = t & 15;
    int lo = lower_bound_dev(batch, N_NODES, r);
    int hi = lower_bound_dev(batch, N_NODES, r + 1);
    float cnt = (float)((hi - lo) > 0 ? (hi - lo) : 1);
    float acc = 0.f;
    #pragma unroll 8
    for (int k = 0; k < C_; k++) acc += P[r * C_ + k] * Wfc[k * 16 + c];
    float logit = acc / cnt + bfc[c];
    __shared__ float l[N_GRAPHS][16];
    l[r][c] = logit;
    __syncthreads();
    float m = -1e30f;
    #pragma unroll
    for (int k = 0; k < 16; k++) m = fmaxf(m, l[r][k]);
    float sum = 0.f;
    #pragma unroll
    for (int k = 0; k < 16; k++) sum += expf(l[r][k] - m);
    out[t] = logit - m - logf(sum);
}

// ---------------- launch ----------------

extern "C" void kernel_launch(void* const* d_in, const int* in_sizes, int n_in,
                              void* d_out, int out_size, void* d_ws, size_t ws_size,
                              hipStream_t stream) {
    const float* x        = (const float*)d_in[0];
    const int*   node_idx = (const int*)  d_in[1];
    const int*   edge_idx = (const int*)  d_in[2];
    const int*   batch    = (const int*)  d_in[3];
    const float* W1       = (const float*)d_in[4];
    const float* b1       = (const float*)d_in[5];
    const float* W2       = (const float*)d_in[6];
    const float* b2       = (const float*)d_in[7];
    const float* Wfc      = (const float*)d_in[8];
    const float* bfc      = (const float*)d_in[9];
    float* out = (float*)d_out;

    char* ws = (char*)d_ws;
    size_t off = 0;
    auto alloc = [&](size_t bytes) -> char* {
        off = (off + 255) & ~(size_t)255;
        char* p = ws + off;
        off += bytes;
        return p;
    };

    ushort_t* xb   = (ushort_t*)alloc((size_t)N_NODES * C_ * 2);   // bf16 x; later reused for h2
    ushort_t* hb   = (ushort_t*)alloc((size_t)N_NODES * C_ * 2);   // h1 (bf16)
    ushort_t* Eb   = (ushort_t*)alloc((size_t)N_EDGES * C_ * 2);   // edge agg (bf16)
    ushort_t* Fb   = (ushort_t*)alloc((size_t)N_EDGES * C_ * 2);   // edge agg @ W (bf16)
    ushort_t* wt1  = (ushort_t*)alloc((size_t)C_ * C_ * 2);
    ushort_t* wt2  = (ushort_t*)alloc((size_t)C_ * C_ * 2);
    // zero-region start
    int*   ecnt   = (int*)  alloc((size_t)N_EDGES * 4);
    int*   ncnt   = (int*)  alloc((size_t)N_NODES * 4);
    int*   ecur   = (int*)  alloc((size_t)N_EDGES * 4);
    int*   ncur   = (int*)  alloc((size_t)N_NODES * 4);
    float* pooled = (float*)alloc((size_t)N_GRAPHS * C_ * 4);
    char*  zend   = ws + off;
    // zero-region end
    int*   eoffs  = (int*)  alloc((size_t)N_EDGES * 4);
    int*   noffs  = (int*)  alloc((size_t)N_NODES * 4);
    int*   csr_en = (int*)  alloc((size_t)NNZ_ * 4);
    int*   csr_ne = (int*)  alloc((size_t)NNZ_ * 4);
    float* binv   = (float*)alloc((size_t)N_EDGES * 4);
    float* dinv   = (float*)alloc((size_t)N_NODES * 4);
    int*   bsum   = (int*)  alloc((size_t)1024 * 4);

    hipMemsetAsync((void*)ecnt, 0, (size_t)(zend - (char*)ecnt), stream);

    // CSR build
    count_kernel<<<(NNZ_ + 255) / 256, 256, 0, stream>>>(node_idx, edge_idx, ecnt, ncnt);
    const int NB_E = (N_EDGES + 1023) / 1024;   // 20
    const int NB_N = (N_NODES + 1023) / 1024;   // 98
    scan_part <<<NB_E, 256, 0, stream>>>(ecnt, N_EDGES, bsum);
    scan_sums <<<1,    256, 0, stream>>>(bsum, NB_E);
    scan_write<<<NB_E, 256, 0, stream>>>(ecnt, N_EDGES, bsum, eoffs);
    scan_part <<<NB_N, 256, 0, stream>>>(ncnt, N_NODES, bsum);
    scan_sums <<<1,    256, 0, stream>>>(bsum, NB_N);
    scan_write<<<NB_N, 256, 0, stream>>>(ncnt, N_NODES, bsum, noffs);
    fill_csr<<<(NNZ_ + 255) / 256, 256, 0, stream>>>(node_idx, edge_idx, eoffs, noffs,
                                                     ecur, ncur, csr_en, csr_ne);
    invert_kernel<<<(N_EDGES + 255) / 256, 256, 0, stream>>>(ecnt, binv, N_EDGES);
    invert_kernel<<<(N_NODES + 255) / 256, 256, 0, stream>>>(ncnt, dinv, N_NODES);

    // conversions
    conv_wt<<<64, 256, 0, stream>>>(W1, wt1);
    conv_wt<<<64, 256, 0, stream>>>(W2, wt2);
    conv_xb<<<(N_NODES * C_ / 8 + 255) / 256, 256, 0, stream>>>(x, xb);

    const int GEB = (N_EDGES + 63) / 64;   // 313 edge-gemm blocks
    // layer 1:  E = Binv*segsum_en(xb);  F = E@W1;  h1 = relu(Dinv*segsum_ne(F) + b1)
    gather_edges_bf<<<N_EDGES / 4, 256, 0, stream>>>(xb, csr_en, eoffs, ecnt, binv, Eb);
    gemm_mfma<<<GEB, 256, 0, stream>>>(Eb, wt1, Fb, N_EDGES);
    gather_nodes_bf<<<N_NODES / 4, 256, 0, stream>>>(Fb, csr_ne, noffs, ncnt, dinv, b1, hb);
    // layer 2 (h2 overwrites xb)
    gather_edges_bf<<<N_EDGES / 4, 256, 0, stream>>>(hb, csr_en, eoffs, ecnt, binv, Eb);
    gemm_mfma<<<GEB, 256, 0, stream>>>(Eb, wt2, Fb, N_EDGES);
    gather_nodes_bf<<<N_NODES / 4, 256, 0, stream>>>(Fb, csr_ne, noffs, ncnt, dinv, b2, xb);
    // head
    pool_kernel<<<dim3(N_GRAPHS, 8), 128, 0, stream>>>(xb, batch, pooled);
    final_kernel<<<1, 1024, 0, stream>>>(pooled, batch, Wfc, bfc, out);
}